// Round 5
// baseline (36.510 us; speedup 1.0000x reference)
//
#include <hip/hip_runtime.h>

// EquivariantMultiheadAttention — B=4, N=128, S=8, CIN=COUT=8, GDIM=7
//
// Softmax over key dims (j,s2) cancels the query factor exp(y_i*w_y1) and the
// biases exp(b_g+b_y) exactly:
//   out[b,i,s1,c] = ( y[b,i,s1,c] + num/den ) * mask[b,i,s1], then @ w_lin^T
//   num = sum_{j,s2} exp(g.wg[c]) * kw * y[b,j,s2,c]
//   den = sum_{j,s2} exp(g.wg[c]) * kw,   kw = mask[b,j,s2] ? exp(y*w_y[c,0]) : 0
//
// R5: async HBM->LDS staging via global_load_lds + per-wave COUNTED vmcnt
// (T3/T4 pattern, the one pipelining mechanism hipcc provably preserves).
// One block per (b,i); the 224 KB slab is consumed in 8 chunks of 128 pairs
// (28 KB), double-buffered in LDS. Each wave stages exactly the 32 pairs it
// consumes -> no barriers in the main loop; vmcnt(7) keeps next chunk's loads
// in flight under current chunk's compute. Table-build barrier is raw
// lgkmcnt(0)+s_barrier so the chunk-0 prefetch is not drained.

namespace {

constexpr int kN = 128, kS = 8, kC = 8, kO = 8, kG = 7;
constexpr int JSTRIDE = 68;          // table row pad: 68%32=4 spreads j-rows
constexpr int CH_PAIRS  = 128;       // pairs per chunk
constexpr int CH_FLOATS = CH_PAIRS * 56;   // 7168 floats = 28672 B
constexpr int NCH = 8;

typedef const __attribute__((address_space(1))) unsigned int* gp_t;
typedef __attribute__((address_space(3))) unsigned int* lp_t;

__global__ __launch_bounds__(256, 1)
void emha_kernel(const float* __restrict__ pg,     // (B,N,N,S,S,G)
                 const float* __restrict__ y,      // (B,N,S,C)
                 const int*   __restrict__ mask,   // (B,N,S) 0/1
                 const float* __restrict__ w_y,    // (C,2)
                 const float* __restrict__ w_g,    // (C,G)
                 const float* __restrict__ w_lin,  // (O,C)
                 float*       __restrict__ out)    // (B,N,S,O)
{
    __shared__ float pay[2][CH_FLOATS];      // 57344 B payload double-buffer
    __shared__ float lds_kw[kN * JSTRIDE];   // 34816 B  kw[j][s2*8+c]
    __shared__ float lds_kv[kN * JSTRIDE];   // 34816 B  kw*y
    __shared__ float red[4][8][16];          // wave, s1, {num[8],den[8]}
    __shared__ float obuf[8][8];             // s1, c

    const int t    = threadIdx.x;            // 0..255
    const int bi   = blockIdx.x;             // b*N + i
    const int b    = bi >> 7;
    const int i    = bi & 127;
    const int w    = t >> 6;                 // wave 0..3
    const int lane = t & 63;

    const float* slab = pg + (size_t)bi * (kN * kS * kS * kG);  // 57344 floats

    // ---- Stage chunk 0 (fire-and-forget; overlaps the table build) ----
    // Wave w stages floats [w*1792, (w+1)*1792) of the chunk = pairs
    // [32w, 32w+32) — exactly the pairs wave w later consumes.
    {
        const float* gs = slab + w * 1792 + lane * 4;
#pragma unroll
        for (int q = 0; q < 7; ++q)
            __builtin_amdgcn_global_load_lds((gp_t)(gs + q * 256),
                                             (lp_t)(&pay[0][w * 1792 + q * 256]),
                                             16, 0, 0);
    }

    // uniform weights (uniform addresses -> scalar loads)
    float wg[kC][kG];
#pragma unroll
    for (int c = 0; c < kC; ++c)
#pragma unroll
        for (int g = 0; g < kG; ++g)
            wg[c][g] = w_g[c * kG + g];

    // ---- Phase 1: key tables for batch b (8192 items, 32/thread) ----
    const float* yb = y    + b * (kN * kS * kC);
    const int*   mb = mask + b * (kN * kS);
    const float  wy0 = w_y[2 * (t & 7)];     // c == idx&7 == t&7 for all k
#pragma unroll
    for (int k = 0; k < 32; ++k) {
        const int idx = t + k * 256;         // j*64 + s2*8 + c
        const float yv = yb[idx];            // coalesced
        const int   m  = mb[idx >> 3];
        const float kwv = m ? __expf(yv * wy0) : 0.0f;
        const int off = (idx >> 6) * JSTRIDE + (idx & 63);
        lds_kw[off] = kwv;
        lds_kv[off] = kwv * yv;
    }
    // Raw barrier: drain LDS writes only — do NOT drain vmcnt (chunk-0
    // prefetch must stay in flight). __syncthreads would force vmcnt(0).
    asm volatile("s_waitcnt lgkmcnt(0)" ::: "memory");
    __builtin_amdgcn_s_barrier();

    // ---- Phase 2: 8 chunks, per-wave double-buffered async pipeline ----
    const int m  = t >> 1;                   // pair within chunk, 0..127
    const int h  = t & 1;                    // s2 half: s2 in [4h, 4h+4)
    float num[kC], den[kC];
#pragma unroll
    for (int c = 0; c < kC; ++c) { num[c] = 0.0f; den[c] = 0.0f; }

#pragma unroll
    for (int c = 0; c < NCH; ++c) {
        // stage chunk c+1 into the other buffer, then wait for chunk c:
        // the 7 new loads stay outstanding (vmcnt(7)) under this compute.
        if (c + 1 < NCH) {
            const float* gs = slab + (c + 1) * CH_FLOATS + w * 1792 + lane * 4;
            float* db = pay[(c + 1) & 1];
#pragma unroll
            for (int q = 0; q < 7; ++q)
                __builtin_amdgcn_global_load_lds((gp_t)(gs + q * 256),
                                                 (lp_t)(db + w * 1792 + q * 256),
                                                 16, 0, 0);
            asm volatile("s_waitcnt vmcnt(7)" ::: "memory");
        } else {
            asm volatile("s_waitcnt vmcnt(0)" ::: "memory");
        }

        // consume this thread's half-pair: 28 floats = 7 x ds_read_b128.
        // start dword 56m+28h -> starts cover banks {0,4,..,28} 8x each:
        // perfectly balanced, no padding needed.
        const float* p = &pay[c & 1][m * 56 + h * 28];
        float4 qv[7];
#pragma unroll
        for (int q = 0; q < 7; ++q)
            qv[q] = reinterpret_cast<const float4*>(p)[q];
        const float* pf = reinterpret_cast<const float*>(qv);

        const int j = 16 * c + (m >> 3);
#pragma unroll
        for (int s2i = 0; s2i < 4; ++s2i) {
            const int lo = j * JSTRIDE + (h * 4 + s2i) * 8;
            const float4 kva = *reinterpret_cast<const float4*>(&lds_kv[lo]);
            const float4 kvb = *reinterpret_cast<const float4*>(&lds_kv[lo + 4]);
            const float4 kwa = *reinterpret_cast<const float4*>(&lds_kw[lo]);
            const float4 kwb = *reinterpret_cast<const float4*>(&lds_kw[lo + 4]);
            const float kv[8] = {kva.x, kva.y, kva.z, kva.w, kvb.x, kvb.y, kvb.z, kvb.w};
            const float kw[8] = {kwa.x, kwa.y, kwa.z, kwa.w, kwb.x, kwb.y, kwb.z, kwb.w};
#pragma unroll
            for (int cc = 0; cc < kC; ++cc) {
                float d =      pf[s2i * kG + 0] * wg[cc][0];
                d = fmaf(pf[s2i * kG + 1], wg[cc][1], d);
                d = fmaf(pf[s2i * kG + 2], wg[cc][2], d);
                d = fmaf(pf[s2i * kG + 3], wg[cc][3], d);
                d = fmaf(pf[s2i * kG + 4], wg[cc][4], d);
                d = fmaf(pf[s2i * kG + 5], wg[cc][5], d);
                d = fmaf(pf[s2i * kG + 6], wg[cc][6], d);
                const float e = __expf(d);
                num[cc] = fmaf(e, kv[cc], num[cc]);
                den[cc] = fmaf(e, kw[cc], den[cc]);
            }
        }
    }

    // ---- Phase 3: reduce lanes sharing s1 = (t>>1)&7 ----
    // free lane bits: 0 (h), 4,5 (m bits 3,4) -> butterfly xor {1,16,32}
#pragma unroll
    for (int c = 0; c < kC; ++c) {
        num[c] += __shfl_xor(num[c], 1);
        num[c] += __shfl_xor(num[c], 16);
        num[c] += __shfl_xor(num[c], 32);
        den[c] += __shfl_xor(den[c], 1);
        den[c] += __shfl_xor(den[c], 16);
        den[c] += __shfl_xor(den[c], 32);
    }
    if (lane < 16 && (lane & 1) == 0) {      // lane = 2*s1
        const int s1 = lane >> 1;
#pragma unroll
        for (int c = 0; c < kC; ++c) {
            red[w][s1][c]     = num[c];
            red[w][s1][c + 8] = den[c];
        }
    }
    __syncthreads();   // vmcnt already 0 (last chunk drained)

    // ---- Phase 4: cross-wave reduce + residual + query mask ----
    if (t < 64) {
        const int s1q = t >> 3, cc = t & 7;
        float ns = 0.0f, ds = 0.0f;
#pragma unroll
        for (int ww = 0; ww < 4; ++ww) { ns += red[ww][s1q][cc]; ds += red[ww][s1q][cc + 8]; }
        const float yv = yb[(i * kS + s1q) * kC + cc];
        const int   mq = mb[i * kS + s1q];
        obuf[s1q][cc] = mq ? (yv + ns / ds) : 0.0f;
    }
    __syncthreads();

    // ---- Phase 5: output linear (c -> o), coalesced 64-float store ----
    if (t < 64) {
        const int s1q = t >> 3, o = t & 7;
        float acc = 0.0f;
#pragma unroll
        for (int c = 0; c < kC; ++c)
            acc = fmaf(obuf[s1q][c], w_lin[o * kC + c], acc);
        out[(size_t)bi * (kS * kO) + t] = acc;
    }
}

} // namespace

extern "C" void kernel_launch(void* const* d_in, const int* in_sizes, int n_in,
                              void* d_out, int out_size, void* d_ws, size_t ws_size,
                              hipStream_t stream)
{
    const float* pg    = (const float*)d_in[0];  // pairwise_g
    const float* y     = (const float*)d_in[1];  // coset_functions
    const int*   mask  = (const int*)  d_in[2];  // mask (bool -> int32)
    const float* w_y   = (const float*)d_in[3];
    // d_in[4] = b_y, d_in[6] = b_g: cancel in the softmax -> unused
    const float* w_g   = (const float*)d_in[5];
    const float* w_lin = (const float*)d_in[7];
    float* out = (float*)d_out;

    emha_kernel<<<4 * kN, 256, 0, stream>>>(pg, y, mask, w_y, w_g, w_lin, out);
}

// Round 6
// 31.850 us; speedup vs baseline: 1.1463x; 1.1463x over previous
//
#include <hip/hip_runtime.h>

// EquivariantMultiheadAttention — B=4, N=128, S=8, CIN=COUT=8, GDIM=7
//
// Softmax over key dims (j,s2) cancels the query factor exp(y_i*w_y1) and the
// biases exp(b_g+b_y) exactly:
//   out[b,i,s1,c] = ( y[b,i,s1,c] + num/den ) * mask[b,i,s1], then @ w_lin^T
//   num = sum_{j,s2} exp(g.wg[c]) * kw * y[b,j,s2,c]
//   den = sum_{j,s2} exp(g.wg[c]) * kw,   kw = mask[b,j,s2] ? exp(y*w_y[c,0]) : 0
//
// R6: many lightweight blocks ("R2 done right"). j-split = 8 -> grid 4096,
// one 28-float half-pair per thread (7 x float4 = 28 VGPR, fits the 128-VGPR
// cap of launch_bounds(256,4) with no spill — R2/R4 held 56-float bursts and
// capsized). Tables are 8.7 KB LDS (16 j rows). Staggered dispatch of 16
// small blocks/CU decorrelates memory and compute phases (R1's 8 barrier-
// locked waves alternated burst/compute in lockstep). Partials to d_ws,
// fused finalize kernel.

namespace {

constexpr int kN = 128, kS = 8, kC = 8, kO = 8, kG = 7;
constexpr int kSplit = 8;                 // j-groups of 16
constexpr int kBI = 4 * kN;               // 512 (b,i) slabs
constexpr int kJB = kN / kSplit;          // 16 j rows per block
// Table row stride: 64 payload + 4 pad floats. Per wave the 4 local-j groups
// read b128s starting at banks {0,4,8,12}+8*s2i, spans disjoint -> at most
// 2-way (the h=0/h=1 halves), which is free (m136).
constexpr int JSTRIDE = 68;

__global__ __launch_bounds__(256, 4)
void emha_partial(const float* __restrict__ pg,     // (B,N,N,S,S,G)
                  const float* __restrict__ y,      // (B,N,S,C)
                  const int*   __restrict__ mask,   // (B,N,S) 0/1
                  const float* __restrict__ w_y,    // (C,2)
                  const float* __restrict__ w_g,    // (C,G)
                  float*       __restrict__ ws)     // (split,bi,s1,16)
{
    __shared__ float lds_kw[kJB * JSTRIDE];  // 4.35 KB  kw[j][s2*8+c]
    __shared__ float lds_kv[kJB * JSTRIDE];  // 4.35 KB  kw*y
    __shared__ float red[4][8][16];          // wave, s1, {num[8],den[8]}

    const int t     = threadIdx.x;           // 0..255
    const int blk   = blockIdx.x;
    const int split = blk & 7;
    const int bi    = blk >> 3;              // b*N + i
    const int b     = bi >> 7;

    const int m = t >> 1;                    // pair within block: j_lo*8+s1
    const int h = t & 1;                     // s2 half: s2 in [4h, 4h+4)

    // ---- Issue this thread's 28-float half-pair burst immediately ----
    // global pair = split*128 + m; half h -> +28 floats.
    const float4* src = reinterpret_cast<const float4*>(
        pg + (size_t)bi * 57344 + (size_t)(split * 128 + m) * 56 + h * 28);
    float4 buf[7];
#pragma unroll
    for (int q = 0; q < 7; ++q) buf[q] = src[q];

    // uniform weights (uniform addresses -> scalar loads)
    float wg[kC][kG];
#pragma unroll
    for (int c = 0; c < kC; ++c)
#pragma unroll
        for (int g = 0; g < kG; ++g)
            wg[c][g] = w_g[c * kG + g];

    // ---- Phase 1: key tables for this block's 16 j rows (1024 items) ----
    const float* yb = y    + b * (kN * kS * kC);
    const int*   mb = mask + b * (kN * kS);
    const float  wy0 = w_y[2 * (t & 7)];     // c == idx&7 == t&7 for all k
#pragma unroll
    for (int k = 0; k < 4; ++k) {
        const int idx  = t + k * 256;        // local: j_lo*64 + s2*8 + c
        const int gidx = split * 1024 + idx;
        const float yv = yb[gidx];           // coalesced
        const int   mm = mb[gidx >> 3];
        const float kwv = mm ? __expf(yv * wy0) : 0.0f;
        const int off = (idx >> 6) * JSTRIDE + (idx & 63);
        lds_kw[off] = kwv;
        lds_kv[off] = kwv * yv;
    }
    __syncthreads();                         // also drains the buf burst

    // ---- Phase 2: 4 s2 of one (j,s1) pair ----
    const int jl = m >> 3;                   // local j row, 0..15
    const float* pf = reinterpret_cast<const float*>(buf);
    float num[kC], den[kC];
#pragma unroll
    for (int c = 0; c < kC; ++c) { num[c] = 0.0f; den[c] = 0.0f; }

#pragma unroll
    for (int s2i = 0; s2i < 4; ++s2i) {
        const int lo = jl * JSTRIDE + (h * 4 + s2i) * 8;
        const float4 kva = *reinterpret_cast<const float4*>(&lds_kv[lo]);
        const float4 kvb = *reinterpret_cast<const float4*>(&lds_kv[lo + 4]);
        const float4 kwa = *reinterpret_cast<const float4*>(&lds_kw[lo]);
        const float4 kwb = *reinterpret_cast<const float4*>(&lds_kw[lo + 4]);
        const float kv[8] = {kva.x, kva.y, kva.z, kva.w, kvb.x, kvb.y, kvb.z, kvb.w};
        const float kw[8] = {kwa.x, kwa.y, kwa.z, kwa.w, kwb.x, kwb.y, kwb.z, kwb.w};
#pragma unroll
        for (int c = 0; c < kC; ++c) {
            float d =      pf[s2i * kG + 0] * wg[c][0];
            d = fmaf(pf[s2i * kG + 1], wg[c][1], d);
            d = fmaf(pf[s2i * kG + 2], wg[c][2], d);
            d = fmaf(pf[s2i * kG + 3], wg[c][3], d);
            d = fmaf(pf[s2i * kG + 4], wg[c][4], d);
            d = fmaf(pf[s2i * kG + 5], wg[c][5], d);
            d = fmaf(pf[s2i * kG + 6], wg[c][6], d);
            const float e = __expf(d);
            num[c] = fmaf(e, kv[c], num[c]);
            den[c] = fmaf(e, kw[c], den[c]);
        }
    }

    // ---- Phase 3: reduce lanes sharing s1 ----
    // t = j_lo*16 + s1*2 + h; in-wave free bits: 0 (h), 4,5 (j_lo low bits)
#pragma unroll
    for (int c = 0; c < kC; ++c) {
        num[c] += __shfl_xor(num[c], 1);
        num[c] += __shfl_xor(num[c], 16);
        num[c] += __shfl_xor(num[c], 32);
        den[c] += __shfl_xor(den[c], 1);
        den[c] += __shfl_xor(den[c], 16);
        den[c] += __shfl_xor(den[c], 32);
    }
    const int w    = t >> 6;
    const int lane = t & 63;
    if (lane < 16 && (lane & 1) == 0) {      // lane = 2*s1
        const int s1 = lane >> 1;
#pragma unroll
        for (int c = 0; c < kC; ++c) {
            red[w][s1][c]     = num[c];
            red[w][s1][c + 8] = den[c];
        }
    }
    __syncthreads();

    // ---- Phase 4: cross-wave sum, write 128 partial floats ----
    if (t < 128) {               // t = s1*16 + idx16
        float v = 0.0f;
#pragma unroll
        for (int ww = 0; ww < 4; ++ww) v += red[ww][t >> 4][t & 15];
        ws[(size_t)(split * kBI + bi) * 128 + t] = v;
    }
}

__global__ __launch_bounds__(256)
void emha_finalize(const float* __restrict__ ws,     // (split,bi,s1,16)
                   const float* __restrict__ y,      // (B,N,S,C)
                   const int*   __restrict__ mask,   // (B,N,S)
                   const float* __restrict__ w_lin,  // (O,C)
                   float*       __restrict__ out)    // (B,N,S,O)
{
    const int tid = blockIdx.x * 256 + threadIdx.x;  // 4096 threads
    const int bi  = tid >> 3;
    const int s1  = tid & 7;

    float4 n0 = {0,0,0,0}, n1 = {0,0,0,0}, d0 = {0,0,0,0}, d1 = {0,0,0,0};
#pragma unroll
    for (int s = 0; s < kSplit; ++s) {
        const float4* pp = reinterpret_cast<const float4*>(
            ws + (size_t)(s * kBI + bi) * 128 + s1 * 16);
        const float4 a = pp[0], bq = pp[1], cq = pp[2], dq = pp[3];
        n0.x += a.x;  n0.y += a.y;  n0.z += a.z;  n0.w += a.w;
        n1.x += bq.x; n1.y += bq.y; n1.z += bq.z; n1.w += bq.w;
        d0.x += cq.x; d0.y += cq.y; d0.z += cq.z; d0.w += cq.w;
        d1.x += dq.x; d1.y += dq.y; d1.z += dq.z; d1.w += dq.w;
    }
    const float nn[8] = {n0.x, n0.y, n0.z, n0.w, n1.x, n1.y, n1.z, n1.w};
    const float dd[8] = {d0.x, d0.y, d0.z, d0.w, d1.x, d1.y, d1.z, d1.w};

    const float* yrow = y + (size_t)bi * 64 + s1 * 8;
    const int mq = mask[bi * 8 + s1];
    float ob[8];
#pragma unroll
    for (int c = 0; c < kC; ++c)
        ob[c] = mq ? (yrow[c] + nn[c] / dd[c]) : 0.0f;

    float o[8];
#pragma unroll
    for (int oo = 0; oo < kO; ++oo) {
        float acc = 0.0f;
#pragma unroll
        for (int c = 0; c < kC; ++c)
            acc = fmaf(ob[c], w_lin[oo * kC + c], acc);
        o[oo] = acc;
    }
    float4* op = reinterpret_cast<float4*>(out + (size_t)bi * 64 + s1 * 8);
    op[0] = make_float4(o[0], o[1], o[2], o[3]);
    op[1] = make_float4(o[4], o[5], o[6], o[7]);
}

} // namespace

extern "C" void kernel_launch(void* const* d_in, const int* in_sizes, int n_in,
                              void* d_out, int out_size, void* d_ws, size_t ws_size,
                              hipStream_t stream)
{
    const float* pg    = (const float*)d_in[0];  // pairwise_g
    const float* y     = (const float*)d_in[1];  // coset_functions
    const int*   mask  = (const int*)  d_in[2];  // mask (bool -> int32)
    const float* w_y   = (const float*)d_in[3];
    // d_in[4] = b_y, d_in[6] = b_g: cancel in the softmax -> unused
    const float* w_g   = (const float*)d_in[5];
    const float* w_lin = (const float*)d_in[7];
    float* out = (float*)d_out;
    float* wsf = (float*)d_ws;                   // 2 MB of scratch used

    emha_partial<<<kBI * kSplit, 256, 0, stream>>>(pg, y, mask, w_y, w_g, wsf);
    emha_finalize<<<16, 256, 0, stream>>>(wsf, y, mask, w_lin, out);
}

// Round 7
// 26.881 us; speedup vs baseline: 1.3582x; 1.1849x over previous
//
#include <hip/hip_runtime.h>

// EquivariantMultiheadAttention — B=4, N=128, S=8, CIN=COUT=8, GDIM=7
//
// Softmax over key dims (j,s2) cancels the query factor exp(y_i*w_y1) and the
// biases exp(b_g+b_y) exactly:
//   out[b,i,s1,c] = ( y[b,i,s1,c] + num/den ) * mask[b,i,s1], then @ w_lin^T
//   num = sum_{j,s2} exp(g.wg[c]) * kw * y[b,j,s2,c]
//   den = sum_{j,s2} exp(g.wg[c]) * kw,   kw = mask[b,j,s2] ? exp(y*w_y[c,0]) : 0
//
// R7: COALESCED loads + wave-autonomous pipeline. All prior ~28µs variants
// shared 224B-strided per-lane loads (64 cache lines / instr, 16B each — 8x
// the transaction count of unit-stride). Here ALL global traffic is unit-
// stride: payload staged per-wave via global_load_lds (1KB/instr), y-tables
// via one coalesced float4 load per group. 8 waves/block, each wave owns 16
// j-rows (4 groups x 32 pairs), private LDS regions, NO main-loop barriers:
// per group {vmcnt(0) -> build kw/kv table -> ds_read payload -> lgkmcnt(0)
// -> issue next group's loads -> register-only compute}. 2 blocks/CU.

namespace {

constexpr int kC = 8, kO = 8, kG = 7;

typedef const __attribute__((address_space(1))) unsigned int* gp_t;
typedef __attribute__((address_space(3))) unsigned int* lp_t;

__device__ __forceinline__ float sgpr_pin(float x) {
    return __int_as_float(__builtin_amdgcn_readfirstlane(__float_as_int(x)));
}

// LDS arena (floats):
//   [0, 14336)        payload: wave w at w*1792 (32 pairs * 56 floats)
//   [14336, 16512)    kwT: wave w at +w*272 (4 j rows, stride 68)
//   [16512, 18688)    kvT: wave w at +w*272
//   [18688, 19712)    red[8][8][16]
//   [19712, 19776)    obuf[8][8]
// total 79104 B -> 2 blocks/CU.

__global__ __launch_bounds__(512, 4)
void emha_kernel(const float* __restrict__ pg,     // (B,N,N,S,S,G)
                 const float* __restrict__ y,      // (B,N,S,C)
                 const int*   __restrict__ mask,   // (B,N,S) 0/1
                 const float* __restrict__ w_y,    // (C,2)
                 const float* __restrict__ w_g,    // (C,G)
                 const float* __restrict__ w_lin,  // (O,C)
                 float*       __restrict__ out)    // (B,N,S,O)
{
    __shared__ __align__(16) float arena[19776];

    const int t  = threadIdx.x;              // 0..511
    const int w  = t >> 6;                   // wave 0..7
    const int l  = t & 63;
    const int bi = blockIdx.x;               // b*N + i
    const int b  = bi >> 7;
    const int i  = bi & 127;

    float* pay  = arena + w * 1792;
    float* kwT  = arena + 14336 + w * 272;
    float* kvT  = arena + 16512 + w * 272;
    float* red  = arena + 18688;             // [8][8][16]
    float* obuf = arena + 19712;             // [8][8]

    const float* slab = pg + (size_t)bi * 57344;
    const float* yb   = y    + b * 8192;
    const int*   mb   = mask + b * 1024;

    // SGPR-pinned weights (keeps VGPR under the (512,4) 128-reg cap)
    float wy0[kC];
#pragma unroll
    for (int c = 0; c < kC; ++c) wy0[c] = sgpr_pin(w_y[2 * c]);
    float wg[kC][kG];
#pragma unroll
    for (int c = 0; c < kC; ++c)
#pragma unroll
        for (int g = 0; g < kG; ++g) wg[c][g] = sgpr_pin(w_g[c * kG + g]);

    // lane roles
    const int w16 = l & 15;                  // table-build slot group
    const int jy  = l >> 4;                  // j offset within group (both maps)
    const int s2y = w16 >> 1;                // table-build s2
    const int cb  = (w16 & 1) * 4;           // table-build c base
    const int jl  = l >> 4;                  // consume: local j
    const int h   = l & 1;                   // consume: s2 half

    // ---- staging helpers (all unit-stride / coalesced) ----
    // payload: 32 pairs * 224B contiguous; dst = uniform base, HW adds lane*16
    auto stage = [&](int g) {
        const float* src = slab + (size_t)(w * 128 + g * 32) * 56 + l * 4;
#pragma unroll
        for (int q = 0; q < 7; ++q)
            __builtin_amdgcn_global_load_lds((gp_t)(src + q * 256),
                                             (lp_t)(pay + q * 256), 16, 0, 0);
    };

    float4 yv; int mv;
    auto loady = [&](int g) {
        const int jg = 16 * w + 4 * g + jy;
        yv = *reinterpret_cast<const float4*>(yb + jg * 64 + w16 * 4);
        mv = mb[jg * 8 + s2y];
    };

    // ---- prologue ----
    stage(0);
    loady(0);

    float num[kC], den[kC];
#pragma unroll
    for (int c = 0; c < kC; ++c) { num[c] = 0.0f; den[c] = 0.0f; }

#pragma unroll 1
    for (int g = 0; g < 4; ++g) {
        // group g payload in LDS + y/mask in regs
        asm volatile("s_waitcnt vmcnt(0)" ::: "memory");
        __builtin_amdgcn_sched_barrier(0);

        // build this group's kw/kv table rows (4 slots per lane)
        {
            const float yv4[4] = {yv.x, yv.y, yv.z, yv.w};
            float kwq[4], kvq[4];
#pragma unroll
            for (int k = 0; k < 4; ++k) {
                const float e = __expf(yv4[k] * wy0[cb + k]);
                kwq[k] = mv ? e : 0.0f;
                kvq[k] = kwq[k] * yv4[k];
            }
            const int toff = jy * 68 + w16 * 4;
            *reinterpret_cast<float4*>(kwT + toff) =
                make_float4(kwq[0], kwq[1], kwq[2], kwq[3]);
            *reinterpret_cast<float4*>(kvT + toff) =
                make_float4(kvq[0], kvq[1], kvq[2], kvq[3]);
        }

        // payload -> registers (7 x ds_read_b128)
        float4 pv[7];
        {
            const float4* ps = reinterpret_cast<const float4*>(pay + l * 28);
#pragma unroll
            for (int q = 0; q < 7; ++q) pv[q] = ps[q];
        }
        // drain payload reads + table writes, THEN issue next group's loads
        asm volatile("s_waitcnt lgkmcnt(0)" ::: "memory");
        __builtin_amdgcn_sched_barrier(0);
        if (g < 3) { stage(g + 1); loady(g + 1); }

        // register-only compute (hides the in-flight loads)
        const float* pf = reinterpret_cast<const float*>(pv);
#pragma unroll
        for (int s2i = 0; s2i < 4; ++s2i) {
            const int ro = jl * 68 + (h * 4 + s2i) * 8;
            const float4 kwa = *reinterpret_cast<const float4*>(kwT + ro);
            const float4 kwb = *reinterpret_cast<const float4*>(kwT + ro + 4);
            const float4 kva = *reinterpret_cast<const float4*>(kvT + ro);
            const float4 kvb = *reinterpret_cast<const float4*>(kvT + ro + 4);
            const float kwv[8] = {kwa.x, kwa.y, kwa.z, kwa.w,
                                  kwb.x, kwb.y, kwb.z, kwb.w};
            const float kvv[8] = {kva.x, kva.y, kva.z, kva.w,
                                  kvb.x, kvb.y, kvb.z, kvb.w};
#pragma unroll
            for (int c = 0; c < kC; ++c) {
                float d =      pf[s2i * kG + 0] * wg[c][0];
                d = fmaf(pf[s2i * kG + 1], wg[c][1], d);
                d = fmaf(pf[s2i * kG + 2], wg[c][2], d);
                d = fmaf(pf[s2i * kG + 3], wg[c][3], d);
                d = fmaf(pf[s2i * kG + 4], wg[c][4], d);
                d = fmaf(pf[s2i * kG + 5], wg[c][5], d);
                d = fmaf(pf[s2i * kG + 6], wg[c][6], d);
                const float e = __expf(d);
                num[c] = fmaf(e, kvv[c], num[c]);
                den[c] = fmaf(e, kwv[c], den[c]);
            }
        }
    }

    // ---- reduce lanes sharing s1 = (l>>1)&7 (free bits: 0=h, 4,5=jl) ----
#pragma unroll
    for (int c = 0; c < kC; ++c) {
        num[c] += __shfl_xor(num[c], 1);
        num[c] += __shfl_xor(num[c], 16);
        num[c] += __shfl_xor(num[c], 32);
        den[c] += __shfl_xor(den[c], 1);
        den[c] += __shfl_xor(den[c], 16);
        den[c] += __shfl_xor(den[c], 32);
    }
    if (l < 16 && (l & 1) == 0) {
        const int s1 = l >> 1;
#pragma unroll
        for (int c = 0; c < kC; ++c) {
            red[w * 128 + s1 * 16 + c]     = num[c];
            red[w * 128 + s1 * 16 + 8 + c] = den[c];
        }
    }
    __syncthreads();

    // ---- cross-wave reduce + residual + query mask ----
    if (t < 64) {
        const int s1q = t >> 3, cc = t & 7;
        float ns = 0.0f, ds = 0.0f;
#pragma unroll
        for (int ww = 0; ww < 8; ++ww) {
            ns += red[ww * 128 + s1q * 16 + cc];
            ds += red[ww * 128 + s1q * 16 + 8 + cc];
        }
        const float yvq = yb[(i * 8 + s1q) * 8 + cc];
        const int   mq  = mb[i * 8 + s1q];
        obuf[s1q * 8 + cc] = mq ? (yvq + ns / ds) : 0.0f;
    }
    __syncthreads();

    // ---- output linear (c -> o), coalesced 64-float store ----
    if (t < 64) {
        const int s1q = t >> 3, o = t & 7;
        float acc = 0.0f;
#pragma unroll
        for (int c = 0; c < kC; ++c)
            acc = fmaf(obuf[s1q * 8 + c], w_lin[o * kC + c], acc);
        out[(size_t)bi * 64 + t] = acc;
    }
}

} // namespace

extern "C" void kernel_launch(void* const* d_in, const int* in_sizes, int n_in,
                              void* d_out, int out_size, void* d_ws, size_t ws_size,
                              hipStream_t stream)
{
    const float* pg    = (const float*)d_in[0];  // pairwise_g
    const float* y     = (const float*)d_in[1];  // coset_functions
    const int*   mask  = (const int*)  d_in[2];  // mask (bool -> int32)
    const float* w_y   = (const float*)d_in[3];
    // d_in[4] = b_y, d_in[6] = b_g: cancel in the softmax -> unused
    const float* w_g   = (const float*)d_in[5];
    const float* w_lin = (const float*)d_in[7];
    float* out = (float*)d_out;

    emha_kernel<<<512, 512, 0, stream>>>(pg, y, mask, w_y, w_g, w_lin, out);
}